// Round 4
// baseline (475.906 us; speedup 1.0000x reference)
//
#include <hip/hip_runtime.h>

namespace {

constexpr int Sn = 256;     // encoder sequence length
constexpr int Tn = 12;      // decoder length
constexpr int HB = 16384;   // half batch: thread handles elems e and e+HB
constexpr float L2E = 1.44269504088896340736f;  // log2(e)

typedef float v2f __attribute__((ext_vector_type(2)));

__device__ __forceinline__ v2f pkfma(v2f a, v2f b, v2f c) {
  return __builtin_elementwise_fma(a, b, c);  // -> v_pk_fma_f32 on gfx950
}

__device__ __forceinline__ float rcp_(float x) { return __builtin_amdgcn_rcpf(x); }

// Direct 2^x; +/-log2e pre-folded into weights (validated R2/R3: absmax
// unchanged at 0.0009765625).
#if __has_builtin(__builtin_amdgcn_exp2f)
__device__ __forceinline__ float exp2_(float x) { return __builtin_amdgcn_exp2f(x); }
#else
__device__ __forceinline__ float exp2_(float x) { return __expf(x * 0.69314718055994530942f); }
#endif

// quad_perm DPP: lane i reads lane sel_i of its 4-lane quad. VALU-rate cross-lane.
template <int CTRL>
__device__ __forceinline__ float qperm(float v) {
  return __int_as_float(
      __builtin_amdgcn_mov_dpp(__float_as_int(v), CTRL, 0xF, 0xF, true));
}
constexpr int DPP_XOR1 = 0xB1;  // [1,0,3,2]
constexpr int DPP_XOR2 = 0x4E;  // [2,3,0,1]
constexpr int DPP_XOR3 = 0x1B;  // [3,2,1,0]
constexpr int DPP_BC0 = 0x00;   // [0,0,0,0]

// Pre-scaled gates: g01 = (-L2E*i, -L2E*f), g23 = (2*L2E*g, -L2E*o).
// Fused single-rcp forms (5 exp + 3 rcp per unit) — R3 numerics, unchanged:
//   i*g = (eg-1)/((1+ei)(eg+1)); f = 1/(1+ef); o*tanh(c) = (ec-1)/((1+eo)(ec+1)).
// tanh exponents clamped at 64 to close the inf/inf NaN path (exact: ratio
// rounds to 1.0f beyond 2^26).
__device__ __forceinline__ float unit_update(v2f g01, v2f g23, float& c) {
  float ei = exp2_(g01.x);
  float ef = exp2_(g01.y);
  float eg = exp2_(fminf(g23.x, 64.0f));
  float eo = exp2_(g23.y);
  float ig = (eg - 1.0f) * rcp_((1.0f + ei) * (eg + 1.0f));
  float fv = rcp_(1.0f + ef);
  c = fmaf(fv, c, ig);
  float ec = exp2_(fminf(c * (2.0f * L2E), 64.0f));
  return (ec - 1.0f) * rcp_((1.0f + eo) * (ec + 1.0f));
}

__device__ __forceinline__ void quad_gather(float h, float* hg) {
  hg[0] = h;
  hg[1] = qperm<DPP_XOR1>(h);
  hg[2] = qperm<DPP_XOR2>(h);
  hg[3] = qperm<DPP_XOR3>(h);
}

// R4: two batch elements per thread. CDNA waves are in-order; R3 showed each
// wave stalls ~1300 cy/step on its serial activation chain with only ~440 cy
// of issue. All waves are resident (grid == SIMD count), so occupancy can't
// hide this — a second independent per-thread element can: its instructions
// fill this element's dependency stalls at compile-time schedule level.
// Weights are shared (loaded once); only state + x-buffers duplicate.
__global__ __launch_bounds__(64) void seq2seq_kernel(
    const float* __restrict__ src, const float* __restrict__ trg,
    const float* __restrict__ eWih0, const float* __restrict__ eWhh0,
    const float* __restrict__ ebih0, const float* __restrict__ ebhh0,
    const float* __restrict__ eWih1, const float* __restrict__ eWhh1,
    const float* __restrict__ ebih1, const float* __restrict__ ebhh1,
    const float* __restrict__ dWih0, const float* __restrict__ dWhh0,
    const float* __restrict__ dbih0, const float* __restrict__ dbhh0,
    const float* __restrict__ dWih1, const float* __restrict__ dWhh1,
    const float* __restrict__ dbih1, const float* __restrict__ dbhh1,
    const float* __restrict__ fcW, const float* __restrict__ fcb,
    float* __restrict__ out) {
  const int slot = blockIdx.x * 64 + threadIdx.x;
  const int e0 = slot >> 2;   // first batch element; second is e0 + HB
  const int u = slot & 3;     // hidden unit owned by this lane

  // Gate rows for this lane: i=u, f=4+u, g=8+u, o=12+u.
  const int ri = u, rf = 4 + u, rg = 8 + u, ro = 12 + u;

  // Activation scales folded into weights: (i,f,o) -L2E (sigmoid), g +2*L2E (tanh).
  const v2f s01 = v2f{-L2E, -L2E};
  const v2f s23 = v2f{2.0f * L2E, -L2E};

  v2f w0x01[8], w0x23[8], w0h01[4], w0h23[4];
  v2f w1i01[4], w1i23[4], w1h01[4], w1h23[4];
#pragma unroll
  for (int j = 0; j < 8; ++j) {
    w0x01[j] = v2f{eWih0[ri * 8 + j], eWih0[rf * 8 + j]} * s01;
    w0x23[j] = v2f{eWih0[rg * 8 + j], eWih0[ro * 8 + j]} * s23;
  }
#pragma unroll
  for (int k = 0; k < 4; ++k) {
    const int kc = u ^ k;
    w0h01[k] = v2f{eWhh0[ri * 4 + kc], eWhh0[rf * 4 + kc]} * s01;
    w0h23[k] = v2f{eWhh0[rg * 4 + kc], eWhh0[ro * 4 + kc]} * s23;
    w1i01[k] = v2f{eWih1[ri * 4 + kc], eWih1[rf * 4 + kc]} * s01;
    w1i23[k] = v2f{eWih1[rg * 4 + kc], eWih1[ro * 4 + kc]} * s23;
    w1h01[k] = v2f{eWhh1[ri * 4 + kc], eWhh1[rf * 4 + kc]} * s01;
    w1h23[k] = v2f{eWhh1[rg * 4 + kc], eWhh1[ro * 4 + kc]} * s23;
  }
  const v2f b0_01 = v2f{ebih0[ri] + ebhh0[ri], ebih0[rf] + ebhh0[rf]} * s01;
  const v2f b0_23 = v2f{ebih0[rg] + ebhh0[rg], ebih0[ro] + ebhh0[ro]} * s23;
  const v2f b1_01 = v2f{ebih1[ri] + ebhh1[ri], ebih1[rf] + ebhh1[rf]} * s01;
  const v2f b1_23 = v2f{ebih1[rg] + ebhh1[rg], ebih1[ro] + ebhh1[ro]} * s23;

  const float4* sp0 = (const float4*)(src + (size_t)e0 * (Sn * 8));
  const float4* sp1 = (const float4*)(src + (size_t)(e0 + HB) * (Sn * 8));

  float h0g[2][4] = {{0, 0, 0, 0}, {0, 0, 0, 0}};  // h0g[p][k] = h0[u^k], elem p
  float h1g[2][4] = {{0, 0, 0, 0}, {0, 0, 0, 0}};
  float c0[2] = {0, 0}, c1[2] = {0, 0};

  // One LSTM step for BOTH elements, interleaved. All array indices are
  // compile-time after unrolling (rule: runtime-indexed reg arrays -> scratch).
  auto step_pair = [&](float4 xa0, float4 xb0, float4 xa1, float4 xb1) {
    float x0[8] = {xa0.x, xa0.y, xa0.z, xa0.w, xb0.x, xb0.y, xb0.z, xb0.w};
    float x1[8] = {xa1.x, xa1.y, xa1.z, xa1.w, xb1.x, xb1.y, xb1.z, xb1.w};
    v2f a01[2] = {b0_01, b0_01}, a23[2] = {b0_23, b0_23};
#pragma unroll
    for (int j = 0; j < 8; ++j) {
      v2f xx0 = v2f{x0[j], x0[j]};
      a01[0] = pkfma(xx0, w0x01[j], a01[0]);
      a23[0] = pkfma(xx0, w0x23[j], a23[0]);
      v2f xx1 = v2f{x1[j], x1[j]};
      a01[1] = pkfma(xx1, w0x01[j], a01[1]);
      a23[1] = pkfma(xx1, w0x23[j], a23[1]);
    }
#pragma unroll
    for (int k = 0; k < 4; ++k) {
#pragma unroll
      for (int p = 0; p < 2; ++p) {
        v2f hh = v2f{h0g[p][k], h0g[p][k]};
        a01[p] = pkfma(hh, w0h01[k], a01[p]);
        a23[p] = pkfma(hh, w0h23[k], a23[p]);
      }
    }
    float h0n[2];
#pragma unroll
    for (int p = 0; p < 2; ++p) h0n[p] = unit_update(a01[p], a23[p], c0[p]);
#pragma unroll
    for (int p = 0; p < 2; ++p) quad_gather(h0n[p], h0g[p]);

    v2f e01[2] = {b1_01, b1_01}, e23[2] = {b1_23, b1_23};
#pragma unroll
    for (int k = 0; k < 4; ++k) {  // h1-dependent half first (independent of h0)
#pragma unroll
      for (int p = 0; p < 2; ++p) {
        v2f hh = v2f{h1g[p][k], h1g[p][k]};
        e01[p] = pkfma(hh, w1h01[k], e01[p]);
        e23[p] = pkfma(hh, w1h23[k], e23[p]);
      }
    }
#pragma unroll
    for (int k = 0; k < 4; ++k) {  // h0-dependent half last (short critical tail)
#pragma unroll
      for (int p = 0; p < 2; ++p) {
        v2f hh = v2f{h0g[p][k], h0g[p][k]};
        e01[p] = pkfma(hh, w1i01[k], e01[p]);
        e23[p] = pkfma(hh, w1i23[k], e23[p]);
      }
    }
    float h1n[2];
#pragma unroll
    for (int p = 0; p < 2; ++p) h1n[p] = unit_update(e01[p], e23[p], c1[p]);
#pragma unroll
    for (int p = 0; p < 2; ++p) quad_gather(h1n[p], h1g[p]);
  };

  // ---------------- encoder: 256 steps = 64 iters x 4 steps ----------------
  // Per elem: A/B double buffers of 2 steps (4 float4) each. Refill issued
  // 2 steps (~2.5k cy) before first use — covers HBM latency. Total buffer
  // regs: 2 elems x 2 bufs x 4 float4 = 64 VGPR.
  float4 A0[4], A1[4], B0[4], B1[4];
#pragma unroll
  for (int j = 0; j < 4; ++j) { A0[j] = sp0[j]; A1[j] = sp1[j]; }          // steps 0-1
#pragma unroll
  for (int j = 0; j < 4; ++j) { B0[j] = sp0[4 + j]; B1[j] = sp1[4 + j]; }  // steps 2-3

  for (int i = 0; i < 64; ++i) {
    step_pair(A0[0], A0[1], A1[0], A1[1]);  // step 4i
    step_pair(A0[2], A0[3], A1[2], A1[3]);  // step 4i+1
    if (i < 63) {  // refill A <- steps 4i+4, 4i+5
#pragma unroll
      for (int j = 0; j < 4; ++j) { A0[j] = sp0[8 * i + 8 + j]; A1[j] = sp1[8 * i + 8 + j]; }
    }
    step_pair(B0[0], B0[1], B1[0], B1[1]);  // step 4i+2
    step_pair(B0[2], B0[3], B1[2], B1[3]);  // step 4i+3
    if (i < 63) {  // refill B <- steps 4i+6, 4i+7
#pragma unroll
      for (int j = 0; j < 4; ++j) { B0[j] = sp0[8 * i + 12 + j]; B1[j] = sp1[8 * i + 12 + j]; }
    }
  }

  // ---- decoder weights (loaded after encoder; encoder weights now dead) ----
  v2f dw0i01 = v2f{dWih0[ri], dWih0[rf]} * s01;
  v2f dw0i23 = v2f{dWih0[rg], dWih0[ro]} * s23;
  v2f dw0h01[4], dw0h23[4], dw1i01[4], dw1i23[4], dw1h01[4], dw1h23[4];
#pragma unroll
  for (int k = 0; k < 4; ++k) {
    const int kc = u ^ k;
    dw0h01[k] = v2f{dWhh0[ri * 4 + kc], dWhh0[rf * 4 + kc]} * s01;
    dw0h23[k] = v2f{dWhh0[rg * 4 + kc], dWhh0[ro * 4 + kc]} * s23;
    dw1i01[k] = v2f{dWih1[ri * 4 + kc], dWih1[rf * 4 + kc]} * s01;
    dw1i23[k] = v2f{dWih1[rg * 4 + kc], dWih1[ro * 4 + kc]} * s23;
    dw1h01[k] = v2f{dWhh1[ri * 4 + kc], dWhh1[rf * 4 + kc]} * s01;
    dw1h23[k] = v2f{dWhh1[rg * 4 + kc], dWhh1[ro * 4 + kc]} * s23;
  }
  const v2f db0_01 = v2f{dbih0[ri] + dbhh0[ri], dbih0[rf] + dbhh0[rf]} * s01;
  const v2f db0_23 = v2f{dbih0[rg] + dbhh0[rg], dbih0[ro] + dbhh0[ro]} * s23;
  const v2f db1_01 = v2f{dbih1[ri] + dbhh1[ri], dbih1[rf] + dbhh1[rf]} * s01;
  const v2f db1_23 = v2f{dbih1[rg] + dbhh1[rg], dbih1[ro] + dbhh1[ro]} * s23;
  float fcw[4];
#pragma unroll
  for (int k = 0; k < 4; ++k) fcw[k] = fcW[u ^ k];
  const float fcbv = fcb[0];

  // ---------------- decoder: 11 steps, both elements ----------------
  float xv[2] = {trg[(size_t)e0 * Tn], trg[(size_t)(e0 + HB) * Tn]};
  if (u == 0) {
    out[(size_t)e0 * Tn] = xv[0];
    out[(size_t)(e0 + HB) * Tn] = xv[1];
  }

  for (int t = 1; t < Tn; ++t) {
    v2f a01[2], a23[2];
#pragma unroll
    for (int p = 0; p < 2; ++p) {
      v2f xx = v2f{xv[p], xv[p]};
      a01[p] = pkfma(xx, dw0i01, db0_01);
      a23[p] = pkfma(xx, dw0i23, db0_23);
    }
#pragma unroll
    for (int k = 0; k < 4; ++k) {
#pragma unroll
      for (int p = 0; p < 2; ++p) {
        v2f hh = v2f{h0g[p][k], h0g[p][k]};
        a01[p] = pkfma(hh, dw0h01[k], a01[p]);
        a23[p] = pkfma(hh, dw0h23[k], a23[p]);
      }
    }
    float h0n[2];
#pragma unroll
    for (int p = 0; p < 2; ++p) h0n[p] = unit_update(a01[p], a23[p], c0[p]);
#pragma unroll
    for (int p = 0; p < 2; ++p) quad_gather(h0n[p], h0g[p]);

    v2f e01[2] = {db1_01, db1_01}, e23[2] = {db1_23, db1_23};
#pragma unroll
    for (int k = 0; k < 4; ++k) {  // h1 half first
#pragma unroll
      for (int p = 0; p < 2; ++p) {
        v2f hh = v2f{h1g[p][k], h1g[p][k]};
        e01[p] = pkfma(hh, dw1h01[k], e01[p]);
        e23[p] = pkfma(hh, dw1h23[k], e23[p]);
      }
    }
#pragma unroll
    for (int k = 0; k < 4; ++k) {  // h0 half last
#pragma unroll
      for (int p = 0; p < 2; ++p) {
        v2f hh = v2f{h0g[p][k], h0g[p][k]};
        e01[p] = pkfma(hh, dw1i01[k], e01[p]);
        e23[p] = pkfma(hh, dw1i23[k], e23[p]);
      }
    }
    float h1n[2];
#pragma unroll
    for (int p = 0; p < 2; ++p) h1n[p] = unit_update(e01[p], e23[p], c1[p]);
#pragma unroll
    for (int p = 0; p < 2; ++p) quad_gather(h1n[p], h1g[p]);

    float pred[2];
#pragma unroll
    for (int p = 0; p < 2; ++p) {
      pred[p] = fcbv;
#pragma unroll
      for (int k = 0; k < 4; ++k) pred[p] = fmaf(h1g[p][k], fcw[k], pred[p]);
      pred[p] = qperm<DPP_BC0>(pred[p]);  // lane0's value to all quad lanes
    }
    if (u == 0) {
      out[(size_t)e0 * Tn + t] = pred[0];
      out[(size_t)(e0 + HB) * Tn + t] = pred[1];
    }
    xv[0] = pred[0];
    xv[1] = pred[1];
  }
}

}  // namespace

extern "C" void kernel_launch(void* const* d_in, const int* in_sizes, int n_in,
                              void* d_out, int out_size, void* d_ws, size_t ws_size,
                              hipStream_t stream) {
  const float* src = (const float*)d_in[0];
  const float* trg = (const float*)d_in[1];
  const float* eWih0 = (const float*)d_in[2];
  const float* eWhh0 = (const float*)d_in[3];
  const float* ebih0 = (const float*)d_in[4];
  const float* ebhh0 = (const float*)d_in[5];
  const float* eWih1 = (const float*)d_in[6];
  const float* eWhh1 = (const float*)d_in[7];
  const float* ebih1 = (const float*)d_in[8];
  const float* ebhh1 = (const float*)d_in[9];
  const float* dWih0 = (const float*)d_in[10];
  const float* dWhh0 = (const float*)d_in[11];
  const float* dbih0 = (const float*)d_in[12];
  const float* dbhh0 = (const float*)d_in[13];
  const float* dWih1 = (const float*)d_in[14];
  const float* dWhh1 = (const float*)d_in[15];
  const float* dbih1 = (const float*)d_in[16];
  const float* dbhh1 = (const float*)d_in[17];
  const float* fcW = (const float*)d_in[18];
  const float* fcb = (const float*)d_in[19];
  float* out = (float*)d_out;

  const int B = 32768;
  const int lanes = (B / 2) * 4;    // 2 elements per thread, 4 lanes per element
  const int block = 64;
  const int grid = lanes / block;   // 1024 blocks -> 1 wave/SIMD, all resident
  seq2seq_kernel<<<grid, block, 0, stream>>>(
      src, trg, eWih0, eWhh0, ebih0, ebhh0, eWih1, eWhh1, ebih1, ebhh1,
      dWih0, dWhh0, dbih0, dbhh0, dWih1, dWhh1, dbih1, dbhh1, fcW, fcb, out);
}

// Round 5
// 470.163 us; speedup vs baseline: 1.0122x; 1.0122x over previous
//
#include <hip/hip_runtime.h>

namespace {

constexpr int Sn = 256;   // encoder sequence length
constexpr int Tn = 12;    // decoder length
constexpr float L2E = 1.44269504088896340736f;  // log2(e)

typedef float v2f __attribute__((ext_vector_type(2)));

__device__ __forceinline__ v2f pkfma(v2f a, v2f b, v2f c) {
  return __builtin_elementwise_fma(a, b, c);  // -> v_pk_fma_f32 on gfx950
}

__device__ __forceinline__ float rcp_(float x) { return __builtin_amdgcn_rcpf(x); }

// Direct 2^x; +/-log2e pre-folded into weights (validated R2/R3).
#if __has_builtin(__builtin_amdgcn_exp2f)
__device__ __forceinline__ float exp2_(float x) { return __builtin_amdgcn_exp2f(x); }
#else
__device__ __forceinline__ float exp2_(float x) { return __expf(x * 0.69314718055994530942f); }
#endif

// quad_perm DPP: lane i reads lane sel_i of its 4-lane quad.
template <int CTRL>
__device__ __forceinline__ float qperm(float v) {
  return __int_as_float(
      __builtin_amdgcn_mov_dpp(__float_as_int(v), CTRL, 0xF, 0xF, true));
}
constexpr int DPP_XOR1 = 0xB1;  // [1,0,3,2]
constexpr int DPP_XOR2 = 0x4E;  // [2,3,0,1]
constexpr int DPP_XOR3 = 0x1B;  // [3,2,1,0]
constexpr int DPP_BC0 = 0x00;   // [0,0,0,0]

// row_shr:4 (0x114), bank_mask 0xA (banks 1,3 = lanes 4-7 / 12-15 per row):
// B-group lanes receive A-group lane (i-4)'s src; A-group lanes keep `old`.
// (GPUOpen: row_shr:N -> dst[i] = src[i-N].)
__device__ __forceinline__ float dpp_shr4_toB(float old, float src) {
  return __int_as_float(__builtin_amdgcn_update_dpp(
      __float_as_int(old), __float_as_int(src), 0x114, 0xF, 0xA, false));
}
// row_shl:4 (0x104), bank_mask 0x5 (banks 0,2 = lanes 0-3 / 8-11): A-group
// lanes receive B-group lane (i+4)'s src; B-group lanes keep `old`.
__device__ __forceinline__ float dpp_shl4_toA(float old, float src) {
  return __int_as_float(__builtin_amdgcn_update_dpp(
      __float_as_int(old), __float_as_int(src), 0x104, 0xF, 0x5, false));
}

// Pre-scaled gates: g01 = (-L2E*i, -L2E*f), g23 = (2*L2E*g, -L2E*o).
// Fused single-rcp forms (5 exp + 3 rcp) — R3 numerics, unchanged.
__device__ __forceinline__ float unit_update(v2f g01, v2f g23, float& c) {
  float ei = exp2_(g01.x);
  float ef = exp2_(g01.y);
  float eg = exp2_(fminf(g23.x, 64.0f));
  float eo = exp2_(g23.y);
  float ig = (eg - 1.0f) * rcp_((1.0f + ei) * (eg + 1.0f));
  float fv = rcp_(1.0f + ef);
  c = fmaf(fv, c, ig);
  float ec = exp2_(fminf(c * (2.0f * L2E), 64.0f));
  return (ec - 1.0f) * rcp_((1.0f + eo) * (ec + 1.0f));
}

__device__ __forceinline__ void quad_gather(float h, float* hg) {
  hg[0] = h;
  hg[1] = qperm<DPP_XOR1>(h);
  hg[2] = qperm<DPP_XOR2>(h);
  hg[3] = qperm<DPP_XOR3>(h);
}

// R5: LAYER-PARALLEL LANES. 8 lanes/element: lanes 0-3 (group A) run layer 0,
// lanes 4-7 (group B) run layer 1, pipelined one step apart. At tick t, A
// computes h0(t) while B computes h1(t-1) — independent given h0(t-1), which
// B receives via one masked DPP row_shr:4 per hg register. Both groups run
// the SAME instructions with different per-lane weights (no divergence), so
// the per-tick serial chain is ONE cell (was two), and the grid doubles to
// 4096 waves = 4 waves/SIMD (R3: 2, R4: 1) for latency hiding.
__global__ __launch_bounds__(64, 4) void seq2seq_kernel(
    const float* __restrict__ src, const float* __restrict__ trg,
    const float* __restrict__ eWih0, const float* __restrict__ eWhh0,
    const float* __restrict__ ebih0, const float* __restrict__ ebhh0,
    const float* __restrict__ eWih1, const float* __restrict__ eWhh1,
    const float* __restrict__ ebih1, const float* __restrict__ ebhh1,
    const float* __restrict__ dWih0, const float* __restrict__ dWhh0,
    const float* __restrict__ dbih0, const float* __restrict__ dbhh0,
    const float* __restrict__ dWih1, const float* __restrict__ dWhh1,
    const float* __restrict__ dbih1, const float* __restrict__ dbhh1,
    const float* __restrict__ fcW, const float* __restrict__ fcb,
    float* __restrict__ out) {
  const int slot = blockIdx.x * 64 + threadIdx.x;
  const int e = slot >> 3;                     // batch element (8 lanes each)
  const int u = slot & 3;                      // unit owned within the quad
  const bool grpB = (threadIdx.x & 4) != 0;    // layer-1 lanes

  const int ri = u, rf = 4 + u, rg = 8 + u, ro = 12 + u;
  const v2f s01 = v2f{-L2E, -L2E};
  const v2f s23 = v2f{2.0f * L2E, -L2E};

  // ---- encoder weights, per lane group ----
  // Input-part win*[8]: A = W0x rows (stride 8, dense j).
  //                     B = W1i col (u^j) for j<4 (matches DPP-received
  //                     h0[u^j] order), ZERO for j>=4 (pad; xs[4..7] hold
  //                     finite x values, contribute exactly 0).
  v2f win01[8], win23[8], wh01[4], wh23[4];
#pragma unroll
  for (int j = 0; j < 8; ++j) {
    v2f vA01 = v2f{eWih0[ri * 8 + j], eWih0[rf * 8 + j]} * s01;
    v2f vA23 = v2f{eWih0[rg * 8 + j], eWih0[ro * 8 + j]} * s23;
    if (j < 4) {
      const int kc = u ^ j;
      v2f vB01 = v2f{eWih1[ri * 4 + kc], eWih1[rf * 4 + kc]} * s01;
      v2f vB23 = v2f{eWih1[rg * 4 + kc], eWih1[ro * 4 + kc]} * s23;
      win01[j] = grpB ? vB01 : vA01;
      win23[j] = grpB ? vB23 : vA23;
    } else {
      win01[j] = grpB ? v2f{0.0f, 0.0f} : vA01;
      win23[j] = grpB ? v2f{0.0f, 0.0f} : vA23;
    }
  }
  {  // own-layer recurrent weights: A = W0h, B = W1h (stride 4, col u^k)
    const float* ph = grpB ? eWhh1 : eWhh0;
#pragma unroll
    for (int k = 0; k < 4; ++k) {
      const int kc = u ^ k;
      wh01[k] = v2f{ph[ri * 4 + kc], ph[rf * 4 + kc]} * s01;
      wh23[k] = v2f{ph[rg * 4 + kc], ph[ro * 4 + kc]} * s23;
    }
  }
  const float* pbi = grpB ? ebih1 : ebih0;
  const float* pbh = grpB ? ebhh1 : ebhh0;
  const v2f b01 = v2f{pbi[ri] + pbh[ri], pbi[rf] + pbh[rf]} * s01;
  const v2f b23 = v2f{pbi[rg] + pbh[rg], pbi[ro] + pbh[ro]} * s23;
  // Tick-0 bias: zero on B. With zero gates the cell maps (h,c)=(0,0)->(0,0)
  // EXACTLY (ig=0, fv=0.5, c=0, h=0), so the not-yet-started layer-1 pipeline
  // stage needs no state reset after tick 0.
  const v2f zb01 = grpB ? v2f{0.0f, 0.0f} : b01;
  const v2f zb23 = grpB ? v2f{0.0f, 0.0f} : b23;

  const float4* sp = (const float4*)(src + (size_t)e * (Sn * 8));

  float hg[4] = {0, 0, 0, 0};  // own-layer h, quad-gathered: hg[k] = h[u^k]
  float cv = 0.0f;             // own-layer c

  // One pipeline tick: A consumes x(t) and h0(t-1); B consumes DPP-received
  // h0(t-1) and h1(t-2). Same instruction stream for both groups.
  auto tick = [&](float4 xa, float4 xb, v2f bb01, v2f bb23) {
    float xs[8] = {xa.x, xa.y, xa.z, xa.w, xb.x, xb.y, xb.z, xb.w};
#pragma unroll
    for (int j = 0; j < 4; ++j) xs[j] = dpp_shr4_toB(xs[j], hg[j]);
    v2f a01 = bb01, a23 = bb23;
#pragma unroll
    for (int j = 0; j < 8; ++j) {
      v2f xx = v2f{xs[j], xs[j]};
      a01 = pkfma(xx, win01[j], a01);
      a23 = pkfma(xx, win23[j], a23);
    }
#pragma unroll
    for (int k = 0; k < 4; ++k) {
      v2f hh = v2f{hg[k], hg[k]};
      a01 = pkfma(hh, wh01[k], a01);
      a23 = pkfma(hh, wh23[k], a23);
    }
    float h = unit_update(a01, a23, cv);
    quad_gather(h, hg);
  };

  // ---------------- encoder: 257 ticks ----------------
  float4 xa = sp[0], xb = sp[1];
  float4 na = sp[2], nb = sp[3];
  tick(xa, xb, zb01, zb23);  // tick 0: A -> h0(0); B -> exact no-op
  for (int t = 1; t < Sn; ++t) {
    float4 ca = na, cb = nb;
    if (t < Sn - 1) { na = sp[2 * t + 2]; nb = sp[2 * t + 3]; }
    tick(ca, cb, b01, b23);
  }
  // Flush tick: B computes h1(255); A's final state must survive.
  {
    float cs = cv, hs0 = hg[0], hs1 = hg[1], hs2 = hg[2], hs3 = hg[3];
    tick(na, nb, b01, b23);  // x args: last tick's x (finite; A result discarded)
    if (!grpB) { cv = cs; hg[0] = hs0; hg[1] = hs1; hg[2] = hs2; hg[3] = hs3; }
  }

  // ---- decoder weights (encoder weights dead; registers reused) ----
  // Input-part dwin*[4]: A = dW0i in slot 0 (input is the scalar pred), zeros
  // elsewhere; B = dW1i col (u^j) (input is DPP-received h0).
  v2f dwin01[4], dwin23[4], dwh01[4], dwh23[4];
#pragma unroll
  for (int j = 0; j < 4; ++j) {
    const int kc = u ^ j;
    v2f vB01 = v2f{dWih1[ri * 4 + kc], dWih1[rf * 4 + kc]} * s01;
    v2f vB23 = v2f{dWih1[rg * 4 + kc], dWih1[ro * 4 + kc]} * s23;
    v2f vA01 = (j == 0) ? v2f{dWih0[ri], dWih0[rf]} * s01 : v2f{0.0f, 0.0f};
    v2f vA23 = (j == 0) ? v2f{dWih0[rg], dWih0[ro]} * s23 : v2f{0.0f, 0.0f};
    dwin01[j] = grpB ? vB01 : vA01;
    dwin23[j] = grpB ? vB23 : vA23;
  }
  {
    const float* ph = grpB ? dWhh1 : dWhh0;
#pragma unroll
    for (int k = 0; k < 4; ++k) {
      const int kc = u ^ k;
      dwh01[k] = v2f{ph[ri * 4 + kc], ph[rf * 4 + kc]} * s01;
      dwh23[k] = v2f{ph[rg * 4 + kc], ph[ro * 4 + kc]} * s23;
    }
  }
  const float* qbi = grpB ? dbih1 : dbih0;
  const float* qbh = grpB ? dbhh1 : dbhh0;
  const v2f db01 = v2f{qbi[ri] + qbh[ri], qbi[rf] + qbh[rf]} * s01;
  const v2f db23 = v2f{qbi[rg] + qbh[rg], qbi[ro] + qbh[ro]} * s23;
  float fcw[4];
#pragma unroll
  for (int k = 0; k < 4; ++k) fcw[k] = fcW[u ^ k];
  const float fcbv = fcb[0];

  // ---------------- decoder: 11 steps, two committed phases each ----------
  // Feedback is serial through both layers, so run layer 0 (commit A) then
  // layer 1 (commit B); the non-owning group computes discarded garbage on a
  // LOCAL state copy. 11 steps -> negligible vs the encoder.
  float xv = trg[(size_t)e * Tn];
  if ((threadIdx.x & 7) == 0) out[(size_t)e * Tn] = xv;

  for (int t = 1; t < Tn; ++t) {
    {  // phase 1: layer 0 on A
      float cT = cv;
      v2f a01 = db01, a23 = db23;
      v2f xx = v2f{xv, xv};
#pragma unroll
      for (int j = 0; j < 4; ++j) {
        a01 = pkfma(xx, dwin01[j], a01);
        a23 = pkfma(xx, dwin23[j], a23);
      }
#pragma unroll
      for (int k = 0; k < 4; ++k) {
        v2f hh = v2f{hg[k], hg[k]};
        a01 = pkfma(hh, dwh01[k], a01);
        a23 = pkfma(hh, dwh23[k], a23);
      }
      float hT = unit_update(a01, a23, cT);
      float hgT[4];
      quad_gather(hT, hgT);
      if (!grpB) { cv = cT; hg[0] = hgT[0]; hg[1] = hgT[1]; hg[2] = hgT[2]; hg[3] = hgT[3]; }
    }
    {  // phase 2: layer 1 on B (receives h0(t) committed in phase 1)
      float cT = cv;
      float xs0 = dpp_shr4_toB(xv, hg[0]);
      float xs1 = dpp_shr4_toB(xv, hg[1]);
      float xs2 = dpp_shr4_toB(xv, hg[2]);
      float xs3 = dpp_shr4_toB(xv, hg[3]);
      v2f a01 = db01, a23 = db23;
      float xsv[4] = {xs0, xs1, xs2, xs3};
#pragma unroll
      for (int j = 0; j < 4; ++j) {
        v2f xx = v2f{xsv[j], xsv[j]};
        a01 = pkfma(xx, dwin01[j], a01);
        a23 = pkfma(xx, dwin23[j], a23);
      }
#pragma unroll
      for (int k = 0; k < 4; ++k) {
        v2f hh = v2f{hg[k], hg[k]};
        a01 = pkfma(hh, dwh01[k], a01);
        a23 = pkfma(hh, dwh23[k], a23);
      }
      float hT = unit_update(a01, a23, cT);
      float hgT[4];
      quad_gather(hT, hgT);
      if (grpB) { cv = cT; hg[0] = hgT[0]; hg[1] = hgT[1]; hg[2] = hgT[2]; hg[3] = hgT[3]; }
    }
    // pred from B's h1(t); broadcast so all 8 lanes carry the identical value.
    float pred = fcbv;
#pragma unroll
    for (int k = 0; k < 4; ++k) pred = fmaf(hg[k], fcw[k], pred);
    pred = qperm<DPP_BC0>(pred);     // within-quad: all lanes = quad-lane 0
    pred = dpp_shl4_toA(pred, pred); // A lanes adopt B-quad's value
    if ((threadIdx.x & 7) == 0) out[(size_t)e * Tn + t] = pred;
    xv = pred;
  }
}

}  // namespace

extern "C" void kernel_launch(void* const* d_in, const int* in_sizes, int n_in,
                              void* d_out, int out_size, void* d_ws, size_t ws_size,
                              hipStream_t stream) {
  const float* src = (const float*)d_in[0];
  const float* trg = (const float*)d_in[1];
  const float* eWih0 = (const float*)d_in[2];
  const float* eWhh0 = (const float*)d_in[3];
  const float* ebih0 = (const float*)d_in[4];
  const float* ebhh0 = (const float*)d_in[5];
  const float* eWih1 = (const float*)d_in[6];
  const float* eWhh1 = (const float*)d_in[7];
  const float* ebih1 = (const float*)d_in[8];
  const float* ebhh1 = (const float*)d_in[9];
  const float* dWih0 = (const float*)d_in[10];
  const float* dWhh0 = (const float*)d_in[11];
  const float* dbih0 = (const float*)d_in[12];
  const float* dbhh0 = (const float*)d_in[13];
  const float* dWih1 = (const float*)d_in[14];
  const float* dWhh1 = (const float*)d_in[15];
  const float* dbih1 = (const float*)d_in[16];
  const float* dbhh1 = (const float*)d_in[17];
  const float* fcW = (const float*)d_in[18];
  const float* fcb = (const float*)d_in[19];
  float* out = (float*)d_out;

  const int B = 32768;
  const int lanes = B * 8;          // 8 lanes per element (layer-split)
  const int block = 64;
  const int grid = lanes / block;   // 4096 blocks -> 16 waves/CU, 4/SIMD
  seq2seq_kernel<<<grid, block, 0, stream>>>(
      src, trg, eWih0, eWhh0, ebih0, ebhh0, eWih1, eWhh1, ebih1, ebhh1,
      dWih0, dWhh0, dbih0, dbhh0, dWih1, dWhh1, dbih1, dbhh1, fcW, fcb, out);
}